// Round 18
// baseline (132.760 us; speedup 1.0000x reference)
//
#include <hip/hip_runtime.h>
#include <math.h>

#define NN 512
#define CC 256
#define HH 8
#define DH 32

typedef float vf4 __attribute__((ext_vector_type(4)));

// ---------------- Kernel A: projections + Wp-fold ----------------
// grid = 256 (two rows n per block), block = 512 — halves redundant weight
// re-reads vs 1-row blocks (512 MB -> 256 MB of L2 request traffic).
__global__ __launch_bounds__(512) void proj_kernel(
    const float* __restrict__ xq, const float* __restrict__ xk, const float* __restrict__ xv,
    const float* __restrict__ Wq, const float* __restrict__ bq,
    const float* __restrict__ Wk, const float* __restrict__ bk,
    const float* __restrict__ Wv, const float* __restrict__ bv,
    const float* __restrict__ Wp, const float* __restrict__ bp,
    float* __restrict__ qf, float* __restrict__ kf, float* __restrict__ vf,
    float* __restrict__ qw, float* __restrict__ qbp)
{
    __shared__ float x_lds[2][3][CC];
    __shared__ float q_lds[2][CC];
    const int t = threadIdx.x;
    const int n0 = blockIdx.x * 2;

    if (t < 384) {
        int hh = t / 192, rem = t % 192;
        int X = rem >> 6, c4 = (rem & 63) * 4;
        const float* xs = (X == 0) ? xq : (X == 1) ? xk : xv;
        *reinterpret_cast<float4*>(&x_lds[hh][X][c4]) =
            *reinterpret_cast<const float4*>(xs + (size_t)(n0 + hh) * CC + c4);
    }
    __syncthreads();

    const int half = t >> 8, j = t & 255;
    const int n = n0 + half;
    {
        float accq = 0.f, acck = 0.f, accv = 0.f;
        const float* wq = Wq + (size_t)j * CC;
        const float* wk = Wk + (size_t)j * CC;
        const float* wv = Wv + (size_t)j * CC;
        #pragma unroll 4
        for (int k4 = 0; k4 < CC / 4; ++k4) {
            float4 a = *reinterpret_cast<const float4*>(wq + k4 * 4);
            float4 b = *reinterpret_cast<const float4*>(wk + k4 * 4);
            float4 d = *reinterpret_cast<const float4*>(wv + k4 * 4);
            const float* x0 = &x_lds[half][0][k4 * 4];
            const float* x1 = &x_lds[half][1][k4 * 4];
            const float* x2 = &x_lds[half][2][k4 * 4];
            accq += x0[0]*a.x + x0[1]*a.y + x0[2]*a.z + x0[3]*a.w;
            acck += x1[0]*b.x + x1[1]*b.y + x1[2]*b.z + x1[3]*b.w;
            accv += x2[0]*d.x + x2[1]*d.y + x2[2]*d.z + x2[3]*d.w;
        }
        float vq = accq + bq[j];
        kf[(size_t)n * CC + j] = acck + bk[j];
        vf[(size_t)n * CC + j] = accv + bv[j];
        qf[(size_t)n * CC + j] = vq;
        q_lds[half][j] = vq;
    }
    __syncthreads();

    // qw fold: each half -> (head-pair hp, j-quad jq); float4 Wp loads
    {
        const int jq = t & 63;
        const int hp = (t >> 6) & 3;
        const int h0 = 2 * hp, h1 = h0 + 1;
        float4 a0 = {0.f, 0.f, 0.f, 0.f}, a1 = {0.f, 0.f, 0.f, 0.f};
        #pragma unroll
        for (int cc = 0; cc < DH; ++cc) {
            float q0 = q_lds[half][h0 * DH + cc];
            float q1 = q_lds[half][h1 * DH + cc];
            float4 w0 = *reinterpret_cast<const float4*>(Wp + (size_t)(h0 * DH + cc) * CC + jq * 4);
            float4 w1 = *reinterpret_cast<const float4*>(Wp + (size_t)(h1 * DH + cc) * CC + jq * 4);
            a0.x += q0 * w0.x; a0.y += q0 * w0.y; a0.z += q0 * w0.z; a0.w += q0 * w0.w;
            a1.x += q1 * w1.x; a1.y += q1 * w1.y; a1.z += q1 * w1.z; a1.w += q1 * w1.w;
        }
        *reinterpret_cast<float4*>(qw + ((size_t)n * HH + h0) * CC + jq * 4) = a0;
        *reinterpret_cast<float4*>(qw + ((size_t)n * HH + h1) * CC + jq * 4) = a1;
    }
    if (t < 16) {
        int hf = t >> 3, h = t & 7;
        float s = 0.f;
        for (int cc = 0; cc < DH; ++cc) s += q_lds[hf][h * DH + cc] * bp[h * DH + cc];
        qbp[(size_t)(n0 + hf) * HH + h] = s;
    }
}

// 16-lane tree reduce of 8 head-partials; lane c (0..15) ends with head
// h = (c&1)*4 + (c&2) + ((c>>2)&1) in u0 (valid for c<8; c>=8 duplicates).
__device__ __forceinline__ float reduce8(const float a[HH], int c) {
    const bool b1 = (c & 1), b2 = (c & 2), b4 = (c & 4);
    float t0 = b1 ? a[0] : a[4], t1 = b1 ? a[1] : a[5],
          t2 = b1 ? a[2] : a[6], t3 = b1 ? a[3] : a[7];
    float r0 = (b1 ? a[4] : a[0]) + __shfl_xor(t0, 1);
    float r1 = (b1 ? a[5] : a[1]) + __shfl_xor(t1, 1);
    float r2 = (b1 ? a[6] : a[2]) + __shfl_xor(t2, 1);
    float r3 = (b1 ? a[7] : a[3]) + __shfl_xor(t3, 1);
    t0 = b2 ? r0 : r2; t1 = b2 ? r1 : r3;
    float s0 = (b2 ? r2 : r0) + __shfl_xor(t0, 2);
    float s1 = (b2 ? r3 : r1) + __shfl_xor(t1, 2);
    t0 = b4 ? s0 : s1;
    float u0 = (b4 ? s1 : s0) + __shfl_xor(t0, 4);
    u0 += __shfl_xor(u0, 8);
    return u0;
}

// ---------------- Kernel B: heterogeneous grid — escore GEMM ∥ E-stream ----------------
// blocks [0,512):   scores_e = q.k^T 64x64 tiles -> esc[n][h][m]  (L2/VALU work)
// blocks [512,4608): scores_p = E.qw, 64-row slab -> scores[n][h][m]  (BW-bound)
__global__ __launch_bounds__(256, 4) void fused_score_kernel(
    const float* __restrict__ E, const float* __restrict__ qf,
    const float* __restrict__ kf, const float* __restrict__ qw,
    float* __restrict__ esc, float* __restrict__ scores)
{
    __shared__ __align__(16) float smem[2 * 64 * 33];
    const int t = threadIdx.x;

    if (blockIdx.x < 512) {
        // ---------- escore: q.k^T per head, 64x64 tile ----------
        const int b = blockIdx.x;
        const int h = b >> 6, nt = (b >> 3) & 7, mt = b & 7;
        const int n0 = nt * 64, m0 = mt * 64;
        float (*q_t)[33] = reinterpret_cast<float(*)[33]>(smem);
        float (*k_t)[33] = reinterpret_cast<float(*)[33]>(smem + 64 * 33);

        #pragma unroll
        for (int it = 0; it < 2; ++it) {
            int idx = t + it * 256;
            int row = idx >> 3, c4 = (idx & 7) * 4;
            float4 qv = *reinterpret_cast<const float4*>(qf + (size_t)(n0 + row) * CC + h * DH + c4);
            float4 kv = *reinterpret_cast<const float4*>(kf + (size_t)(m0 + row) * CC + h * DH + c4);
            q_t[row][c4] = qv.x; q_t[row][c4+1] = qv.y; q_t[row][c4+2] = qv.z; q_t[row][c4+3] = qv.w;
            k_t[row][c4] = kv.x; k_t[row][c4+1] = kv.y; k_t[row][c4+2] = kv.z; k_t[row][c4+3] = kv.w;
        }
        __syncthreads();

        const int tx = t & 15, ty = t >> 4;
        float acc[4][4];
        #pragma unroll
        for (int i = 0; i < 4; ++i)
            #pragma unroll
            for (int jq = 0; jq < 4; ++jq) acc[i][jq] = 0.f;

        for (int cc = 0; cc < DH; ++cc) {
            float qa[4], kb[4];
            #pragma unroll
            for (int i = 0; i < 4; ++i) qa[i] = q_t[ty * 4 + i][cc];
            #pragma unroll
            for (int jq = 0; jq < 4; ++jq) kb[jq] = k_t[tx * 4 + jq][cc];
            #pragma unroll
            for (int i = 0; i < 4; ++i)
                #pragma unroll
                for (int jq = 0; jq < 4; ++jq) acc[i][jq] += qa[i] * kb[jq];
        }

        #pragma unroll
        for (int i = 0; i < 4; ++i) {
            float4 v = {acc[i][0], acc[i][1], acc[i][2], acc[i][3]};
            *reinterpret_cast<float4*>(
                esc + ((size_t)(n0 + ty * 4 + i) * HH + h) * NN + m0 + tx * 4) = v;
        }
    } else {
        // ---------- estream: E.qw over a 64-row slab, full-row wave bursts ----------
        const int b = blockIdx.x - 512;
        const int n = b >> 3, slab = b & 7;
        const int m0 = slab * 64;
        const int v = t >> 6, l = t & 63;
        const int c = l & 15;
        float (*s_out)[68] = reinterpret_cast<float(*)[68]>(smem);

        vf4 qwr[HH];
        #pragma unroll
        for (int h = 0; h < HH; ++h)
            qwr[h] = *reinterpret_cast<const vf4*>(qw + ((size_t)n * HH + h) * CC + l * 4);

        const float* Ebase = E + ((size_t)n * NN + m0 + v * 16) * CC;

        vf4 eA[8], eB[8];
        #pragma unroll
        for (int it = 0; it < 8; ++it)
            eA[it] = *reinterpret_cast<const vf4*>(Ebase + (size_t)it * CC + l * 4);
        #pragma unroll
        for (int it = 0; it < 8; ++it)
            eB[it] = *reinterpret_cast<const vf4*>(Ebase + (size_t)(8 + it) * CC + l * 4);

        #pragma unroll
        for (int it = 0; it < 8; ++it) {
            float a[HH];
            #pragma unroll
            for (int h = 0; h < HH; ++h)
                a[h] = eA[it][0]*qwr[h][0] + eA[it][1]*qwr[h][1] +
                       eA[it][2]*qwr[h][2] + eA[it][3]*qwr[h][3];
            float u0 = reduce8(a, c);
            u0 += __shfl_xor(u0, 16);
            u0 += __shfl_xor(u0, 32);
            if (l < 8) {
                int h = (c & 1) * 4 + (c & 2) + ((c >> 2) & 1);
                s_out[h][v * 16 + it] = u0;
            }
        }
        #pragma unroll
        for (int it = 0; it < 8; ++it) {
            float a[HH];
            #pragma unroll
            for (int h = 0; h < HH; ++h)
                a[h] = eB[it][0]*qwr[h][0] + eB[it][1]*qwr[h][1] +
                       eB[it][2]*qwr[h][2] + eB[it][3]*qwr[h][3];
            float u0 = reduce8(a, c);
            u0 += __shfl_xor(u0, 16);
            u0 += __shfl_xor(u0, 32);
            if (l < 8) {
                int h = (c & 1) * 4 + (c & 2) + ((c >> 2) & 1);
                s_out[h][v * 16 + 8 + it] = u0;
            }
        }
        __syncthreads();

        // coalesced flush: scores[n][h][m0+row]
        {
            int h0 = t >> 6, row = t & 63;
            scores[((size_t)n * HH + h0) * NN + m0 + row] = s_out[h0][row];
            int h1 = h0 + 4;
            scores[((size_t)n * HH + h1) * NN + m0 + row] = s_out[h1][row];
        }
    }
}

// ---------------- Kernel D: softmax(esc + scores) + attn write + hidden ----------------
// grid = 512 (one n per block), block = 512; wave w handles head w.
// float4 score path: lane l owns m = 4l..4l+3 and 256+4l..256+4l+3.
__global__ __launch_bounds__(512) void softmax_hidden_kernel(
    const float* __restrict__ esc, const float* __restrict__ scores,
    const float* __restrict__ qbp, const float* __restrict__ vf,
    float* __restrict__ attn_out, float* __restrict__ out_hidden)
{
    const int n = blockIdx.x;
    const int t = threadIdx.x;
    const int w = t >> 6, l = t & 63;

    __shared__ float s_lds[HH][NN + 4];   // 16.1 KB (probs); stride 516 keeps 16B align
    __shared__ float part_lds[HH][CC];    // 8 KB (hidden partials)

    {
        const int h = w;
        const float qb = qbp[(size_t)n * HH + h];
        const float scale = 0.17677669529663687f;  // 1/sqrt(32)
        const float* ep = esc    + ((size_t)n * HH + h) * NN;
        const float* sp = scores + ((size_t)n * HH + h) * NN;
        vf4 e0 = *reinterpret_cast<const vf4*>(ep + l * 4);
        vf4 s0 = *reinterpret_cast<const vf4*>(sp + l * 4);
        vf4 e1 = *reinterpret_cast<const vf4*>(ep + 256 + l * 4);
        vf4 s1 = *reinterpret_cast<const vf4*>(sp + 256 + l * 4);
        vf4 A = (e0 + s0 + qb) * scale;
        vf4 B = (e1 + s1 + qb) * scale;
        float mx = fmaxf(fmaxf(fmaxf(A[0], A[1]), fmaxf(A[2], A[3])),
                         fmaxf(fmaxf(B[0], B[1]), fmaxf(B[2], B[3])));
        #pragma unroll
        for (int off = 32; off > 0; off >>= 1) mx = fmaxf(mx, __shfl_xor(mx, off));
        #pragma unroll
        for (int i = 0; i < 4; ++i) { A[i] = __expf(A[i] - mx); B[i] = __expf(B[i] - mx); }
        float sum = A[0] + A[1] + A[2] + A[3] + B[0] + B[1] + B[2] + B[3];
        #pragma unroll
        for (int off = 32; off > 0; off >>= 1) sum += __shfl_xor(sum, off);
        float inv = 1.0f / sum;
        A *= inv; B *= inv;
        *reinterpret_cast<vf4*>(&s_lds[h][l * 4]) = A;
        *reinterpret_cast<vf4*>(&s_lds[h][256 + l * 4]) = B;
        vf4* ao = reinterpret_cast<vf4*>(attn_out + ((size_t)h * NN + n) * NN);
        __builtin_nontemporal_store(A, ao + l);
        __builtin_nontemporal_store(B, ao + 64 + l);
    }
    __syncthreads();

    // hidden[n][j] = sum_m attn[h][m] * v[m][j], h = j>>5 (vf L2-resident here)
    {
        const int quad = t & 63;           // output cols quad*4..quad*4+3
        const int slice = w;               // m slice of 64
        const int h = quad >> 3;
        float4 a4 = {0.f, 0.f, 0.f, 0.f};
        const float* vb = vf + quad * 4;
        for (int mm = 0; mm < 64; ++mm) {
            int m = slice * 64 + mm;
            float a = s_lds[h][m];
            float4 vv = *reinterpret_cast<const float4*>(vb + (size_t)m * CC);
            a4.x += a * vv.x; a4.y += a * vv.y; a4.z += a * vv.z; a4.w += a * vv.w;
        }
        *reinterpret_cast<float4*>(&part_lds[slice][quad * 4]) = a4;
    }
    __syncthreads();
    if (t < 256) {
        float s = 0.f;
        #pragma unroll
        for (int sl = 0; sl < 8; ++sl) s += part_lds[sl][t];
        out_hidden[(size_t)n * CC + t] = s;
    }
}

// ---------------- launch ----------------
extern "C" void kernel_launch(void* const* d_in, const int* in_sizes, int n_in,
                              void* d_out, int out_size, void* d_ws, size_t ws_size,
                              hipStream_t stream) {
    const float* xq = (const float*)d_in[0];
    const float* xk = (const float*)d_in[1];
    const float* xv = (const float*)d_in[2];
    const float* E  = (const float*)d_in[3];
    const float* Wq = (const float*)d_in[4];
    const float* bq = (const float*)d_in[5];
    const float* Wk = (const float*)d_in[6];
    const float* bk = (const float*)d_in[7];
    const float* Wv = (const float*)d_in[8];
    const float* bv = (const float*)d_in[9];
    const float* Wp = (const float*)d_in[10];
    const float* bp = (const float*)d_in[11];

    float* ws = (float*)d_ws;
    float* qf     = ws;                          // 512*256
    float* kf     = qf + NN * CC;                // 512*256
    float* vf     = kf + NN * CC;                // 512*256
    float* qw     = vf + NN * CC;                // 512*8*256
    float* qbp    = qw + (size_t)NN * HH * CC;   // 512*8
    float* esc    = qbp + NN * HH;               // 512*8*512 (q.k^T scores)
    float* scores = esc + (size_t)NN * HH * NN;  // 512*8*512 (E.qw scores)

    float* out_hidden = (float*)d_out;            // 512*256
    float* out_attn   = out_hidden + NN * CC;     // 8*512*512

    proj_kernel<<<NN / 2, 512, 0, stream>>>(xq, xk, xv, Wq, bq, Wk, bk, Wv, bv, Wp, bp,
                                            qf, kf, vf, qw, qbp);
    fused_score_kernel<<<512 + NN * 8, 256, 0, stream>>>(E, qf, kf, qw, esc, scores);
    softmax_hidden_kernel<<<NN, 512, 0, stream>>>(esc, scores, qbp, vf,
                                                  out_attn, out_hidden);
}

// Round 19
// 117.209 us; speedup vs baseline: 1.1327x; 1.1327x over previous
//
#include <hip/hip_runtime.h>
#include <math.h>

#define NN 512
#define CC 256
#define HH 8
#define DH 32

typedef float vf4 __attribute__((ext_vector_type(4)));

// ---------------- Kernel A: projections + Wp-fold ----------------
// grid = 512 (one n per block), block = 256.
// NOTE (r18 post-mortem): 2-rows-per-block regressed 117->133us — proj is
// weight-fetch-latency-bound; 512 thin blocks hide that latency best.
__global__ __launch_bounds__(256) void proj_kernel(
    const float* __restrict__ xq, const float* __restrict__ xk, const float* __restrict__ xv,
    const float* __restrict__ Wq, const float* __restrict__ bq,
    const float* __restrict__ Wk, const float* __restrict__ bk,
    const float* __restrict__ Wv, const float* __restrict__ bv,
    const float* __restrict__ Wp, const float* __restrict__ bp,
    float* __restrict__ qf, float* __restrict__ kf, float* __restrict__ vf,
    float* __restrict__ qw, float* __restrict__ qbp)
{
    __shared__ float x_lds[3][CC];
    __shared__ float q_lds[CC];
    const int t = threadIdx.x;
    const int n = blockIdx.x;

    if (t < 192) {
        int X = t >> 6, c4 = (t & 63) * 4;
        const float* xs = (X == 0) ? xq : (X == 1) ? xk : xv;
        *reinterpret_cast<float4*>(&x_lds[X][c4]) =
            *reinterpret_cast<const float4*>(xs + (size_t)n * CC + c4);
    }
    __syncthreads();

    const int j = t;
    {
        float accq = 0.f, acck = 0.f, accv = 0.f;
        const float* wq = Wq + (size_t)j * CC;
        const float* wk = Wk + (size_t)j * CC;
        const float* wv = Wv + (size_t)j * CC;
        #pragma unroll 4
        for (int k4 = 0; k4 < CC / 4; ++k4) {
            float4 a = *reinterpret_cast<const float4*>(wq + k4 * 4);
            float4 b = *reinterpret_cast<const float4*>(wk + k4 * 4);
            float4 d = *reinterpret_cast<const float4*>(wv + k4 * 4);
            const float* x0 = &x_lds[0][k4 * 4];
            const float* x1 = &x_lds[1][k4 * 4];
            const float* x2 = &x_lds[2][k4 * 4];
            accq += x0[0]*a.x + x0[1]*a.y + x0[2]*a.z + x0[3]*a.w;
            acck += x1[0]*b.x + x1[1]*b.y + x1[2]*b.z + x1[3]*b.w;
            accv += x2[0]*d.x + x2[1]*d.y + x2[2]*d.z + x2[3]*d.w;
        }
        float vq = accq + bq[j];
        kf[(size_t)n * CC + j] = acck + bk[j];
        vf[(size_t)n * CC + j] = accv + bv[j];
        qf[(size_t)n * CC + j] = vq;
        q_lds[j] = vq;
    }
    __syncthreads();

    // qw fold: thread -> (head-pair hp, j-quad jq); float4 Wp loads
    {
        const int jq = t & 63;
        const int hp = t >> 6;
        const int h0 = 2 * hp, h1 = h0 + 1;
        float4 a0 = {0.f, 0.f, 0.f, 0.f}, a1 = {0.f, 0.f, 0.f, 0.f};
        #pragma unroll
        for (int cc = 0; cc < DH; ++cc) {
            float q0 = q_lds[h0 * DH + cc];
            float q1 = q_lds[h1 * DH + cc];
            float4 w0 = *reinterpret_cast<const float4*>(Wp + (size_t)(h0 * DH + cc) * CC + jq * 4);
            float4 w1 = *reinterpret_cast<const float4*>(Wp + (size_t)(h1 * DH + cc) * CC + jq * 4);
            a0.x += q0 * w0.x; a0.y += q0 * w0.y; a0.z += q0 * w0.z; a0.w += q0 * w0.w;
            a1.x += q1 * w1.x; a1.y += q1 * w1.y; a1.z += q1 * w1.z; a1.w += q1 * w1.w;
        }
        *reinterpret_cast<float4*>(qw + ((size_t)n * HH + h0) * CC + jq * 4) = a0;
        *reinterpret_cast<float4*>(qw + ((size_t)n * HH + h1) * CC + jq * 4) = a1;
    }
    if (t < HH) {
        float s = 0.f;
        for (int cc = 0; cc < DH; ++cc) s += q_lds[t * DH + cc] * bp[t * DH + cc];
        qbp[(size_t)n * HH + t] = s;
    }
}

// 16-lane tree reduce of 8 head-partials; lane c (0..15) ends with head
// h = (c&1)*4 + (c&2) + ((c>>2)&1) in u0 (valid for c<8; c>=8 duplicates).
__device__ __forceinline__ float reduce8(const float a[HH], int c) {
    const bool b1 = (c & 1), b2 = (c & 2), b4 = (c & 4);
    float t0 = b1 ? a[0] : a[4], t1 = b1 ? a[1] : a[5],
          t2 = b1 ? a[2] : a[6], t3 = b1 ? a[3] : a[7];
    float r0 = (b1 ? a[4] : a[0]) + __shfl_xor(t0, 1);
    float r1 = (b1 ? a[5] : a[1]) + __shfl_xor(t1, 1);
    float r2 = (b1 ? a[6] : a[2]) + __shfl_xor(t2, 1);
    float r3 = (b1 ? a[7] : a[3]) + __shfl_xor(t3, 1);
    t0 = b2 ? r0 : r2; t1 = b2 ? r1 : r3;
    float s0 = (b2 ? r2 : r0) + __shfl_xor(t0, 2);
    float s1 = (b2 ? r3 : r1) + __shfl_xor(t1, 2);
    t0 = b4 ? s0 : s1;
    float u0 = (b4 ? s1 : s0) + __shfl_xor(t0, 4);
    u0 += __shfl_xor(u0, 8);
    return u0;
}

// ---------------- Kernel B: heterogeneous grid — escore GEMM ∥ E-stream ----------------
// blocks [0,512):   scores_e = q.k^T 64x64 tiles -> esc[n][h][m]  (L2/VALU work)
// blocks [512,4608): scores_p = E.qw, 64-row slab -> scores[n][h][m]  (BW-bound)
__global__ __launch_bounds__(256, 4) void fused_score_kernel(
    const float* __restrict__ E, const float* __restrict__ qf,
    const float* __restrict__ kf, const float* __restrict__ qw,
    float* __restrict__ esc, float* __restrict__ scores)
{
    __shared__ __align__(16) float smem[2 * 64 * 33];
    const int t = threadIdx.x;

    if (blockIdx.x < 512) {
        // ---------- escore: q.k^T per head, 64x64 tile ----------
        const int b = blockIdx.x;
        const int h = b >> 6, nt = (b >> 3) & 7, mt = b & 7;
        const int n0 = nt * 64, m0 = mt * 64;
        float (*q_t)[33] = reinterpret_cast<float(*)[33]>(smem);
        float (*k_t)[33] = reinterpret_cast<float(*)[33]>(smem + 64 * 33);

        #pragma unroll
        for (int it = 0; it < 2; ++it) {
            int idx = t + it * 256;
            int row = idx >> 3, c4 = (idx & 7) * 4;
            float4 qv = *reinterpret_cast<const float4*>(qf + (size_t)(n0 + row) * CC + h * DH + c4);
            float4 kv = *reinterpret_cast<const float4*>(kf + (size_t)(m0 + row) * CC + h * DH + c4);
            q_t[row][c4] = qv.x; q_t[row][c4+1] = qv.y; q_t[row][c4+2] = qv.z; q_t[row][c4+3] = qv.w;
            k_t[row][c4] = kv.x; k_t[row][c4+1] = kv.y; k_t[row][c4+2] = kv.z; k_t[row][c4+3] = kv.w;
        }
        __syncthreads();

        const int tx = t & 15, ty = t >> 4;
        float acc[4][4];
        #pragma unroll
        for (int i = 0; i < 4; ++i)
            #pragma unroll
            for (int jq = 0; jq < 4; ++jq) acc[i][jq] = 0.f;

        for (int cc = 0; cc < DH; ++cc) {
            float qa[4], kb[4];
            #pragma unroll
            for (int i = 0; i < 4; ++i) qa[i] = q_t[ty * 4 + i][cc];
            #pragma unroll
            for (int jq = 0; jq < 4; ++jq) kb[jq] = k_t[tx * 4 + jq][cc];
            #pragma unroll
            for (int i = 0; i < 4; ++i)
                #pragma unroll
                for (int jq = 0; jq < 4; ++jq) acc[i][jq] += qa[i] * kb[jq];
        }

        #pragma unroll
        for (int i = 0; i < 4; ++i) {
            float4 v = {acc[i][0], acc[i][1], acc[i][2], acc[i][3]};
            *reinterpret_cast<float4*>(
                esc + ((size_t)(n0 + ty * 4 + i) * HH + h) * NN + m0 + tx * 4) = v;
        }
    } else {
        // ---------- estream: E.qw over a 64-row slab, full-row wave bursts ----------
        const int b = blockIdx.x - 512;
        const int n = b >> 3, slab = b & 7;
        const int m0 = slab * 64;
        const int v = t >> 6, l = t & 63;
        const int c = l & 15;
        float (*s_out)[68] = reinterpret_cast<float(*)[68]>(smem);

        vf4 qwr[HH];
        #pragma unroll
        for (int h = 0; h < HH; ++h)
            qwr[h] = *reinterpret_cast<const vf4*>(qw + ((size_t)n * HH + h) * CC + l * 4);

        const float* Ebase = E + ((size_t)n * NN + m0 + v * 16) * CC;

        vf4 eA[8], eB[8];
        #pragma unroll
        for (int it = 0; it < 8; ++it)
            eA[it] = *reinterpret_cast<const vf4*>(Ebase + (size_t)it * CC + l * 4);
        #pragma unroll
        for (int it = 0; it < 8; ++it)
            eB[it] = *reinterpret_cast<const vf4*>(Ebase + (size_t)(8 + it) * CC + l * 4);

        #pragma unroll
        for (int it = 0; it < 8; ++it) {
            float a[HH];
            #pragma unroll
            for (int h = 0; h < HH; ++h)
                a[h] = eA[it][0]*qwr[h][0] + eA[it][1]*qwr[h][1] +
                       eA[it][2]*qwr[h][2] + eA[it][3]*qwr[h][3];
            float u0 = reduce8(a, c);
            u0 += __shfl_xor(u0, 16);
            u0 += __shfl_xor(u0, 32);
            if (l < 8) {
                int h = (c & 1) * 4 + (c & 2) + ((c >> 2) & 1);
                s_out[h][v * 16 + it] = u0;
            }
        }
        #pragma unroll
        for (int it = 0; it < 8; ++it) {
            float a[HH];
            #pragma unroll
            for (int h = 0; h < HH; ++h)
                a[h] = eB[it][0]*qwr[h][0] + eB[it][1]*qwr[h][1] +
                       eB[it][2]*qwr[h][2] + eB[it][3]*qwr[h][3];
            float u0 = reduce8(a, c);
            u0 += __shfl_xor(u0, 16);
            u0 += __shfl_xor(u0, 32);
            if (l < 8) {
                int h = (c & 1) * 4 + (c & 2) + ((c >> 2) & 1);
                s_out[h][v * 16 + 8 + it] = u0;
            }
        }
        __syncthreads();

        // coalesced flush: scores[n][h][m0+row]
        {
            int h0 = t >> 6, row = t & 63;
            scores[((size_t)n * HH + h0) * NN + m0 + row] = s_out[h0][row];
            int h1 = h0 + 4;
            scores[((size_t)n * HH + h1) * NN + m0 + row] = s_out[h1][row];
        }
    }
}

// ---------------- Kernel D: softmax(esc + scores) + attn write + hidden ----------------
// grid = 512 (one n per block), block = 512; wave w handles head w.
// float4 score path: lane l owns m = 4l..4l+3 and 256+4l..256+4l+3.
__global__ __launch_bounds__(512) void softmax_hidden_kernel(
    const float* __restrict__ esc, const float* __restrict__ scores,
    const float* __restrict__ qbp, const float* __restrict__ vf,
    float* __restrict__ attn_out, float* __restrict__ out_hidden)
{
    const int n = blockIdx.x;
    const int t = threadIdx.x;
    const int w = t >> 6, l = t & 63;

    __shared__ float s_lds[HH][NN + 4];   // 16.1 KB (probs); stride 516 keeps 16B align
    __shared__ float part_lds[HH][CC];    // 8 KB (hidden partials)

    {
        const int h = w;
        const float qb = qbp[(size_t)n * HH + h];
        const float scale = 0.17677669529663687f;  // 1/sqrt(32)
        const float* ep = esc    + ((size_t)n * HH + h) * NN;
        const float* sp = scores + ((size_t)n * HH + h) * NN;
        vf4 e0 = *reinterpret_cast<const vf4*>(ep + l * 4);
        vf4 s0 = *reinterpret_cast<const vf4*>(sp + l * 4);
        vf4 e1 = *reinterpret_cast<const vf4*>(ep + 256 + l * 4);
        vf4 s1 = *reinterpret_cast<const vf4*>(sp + 256 + l * 4);
        vf4 A = (e0 + s0 + qb) * scale;
        vf4 B = (e1 + s1 + qb) * scale;
        float mx = fmaxf(fmaxf(fmaxf(A[0], A[1]), fmaxf(A[2], A[3])),
                         fmaxf(fmaxf(B[0], B[1]), fmaxf(B[2], B[3])));
        #pragma unroll
        for (int off = 32; off > 0; off >>= 1) mx = fmaxf(mx, __shfl_xor(mx, off));
        #pragma unroll
        for (int i = 0; i < 4; ++i) { A[i] = __expf(A[i] - mx); B[i] = __expf(B[i] - mx); }
        float sum = A[0] + A[1] + A[2] + A[3] + B[0] + B[1] + B[2] + B[3];
        #pragma unroll
        for (int off = 32; off > 0; off >>= 1) sum += __shfl_xor(sum, off);
        float inv = 1.0f / sum;
        A *= inv; B *= inv;
        *reinterpret_cast<vf4*>(&s_lds[h][l * 4]) = A;
        *reinterpret_cast<vf4*>(&s_lds[h][256 + l * 4]) = B;
        vf4* ao = reinterpret_cast<vf4*>(attn_out + ((size_t)h * NN + n) * NN);
        __builtin_nontemporal_store(A, ao + l);
        __builtin_nontemporal_store(B, ao + 64 + l);
    }
    __syncthreads();

    // hidden[n][j] = sum_m attn[h][m] * v[m][j], h = j>>5 (vf L2-resident here)
    {
        const int quad = t & 63;           // output cols quad*4..quad*4+3
        const int slice = w;               // m slice of 64
        const int h = quad >> 3;
        float4 a4 = {0.f, 0.f, 0.f, 0.f};
        const float* vb = vf + quad * 4;
        for (int mm = 0; mm < 64; ++mm) {
            int m = slice * 64 + mm;
            float a = s_lds[h][m];
            float4 vv = *reinterpret_cast<const float4*>(vb + (size_t)m * CC);
            a4.x += a * vv.x; a4.y += a * vv.y; a4.z += a * vv.z; a4.w += a * vv.w;
        }
        *reinterpret_cast<float4*>(&part_lds[slice][quad * 4]) = a4;
    }
    __syncthreads();
    if (t < 256) {
        float s = 0.f;
        #pragma unroll
        for (int sl = 0; sl < 8; ++sl) s += part_lds[sl][t];
        out_hidden[(size_t)n * CC + t] = s;
    }
}

// ---------------- launch ----------------
extern "C" void kernel_launch(void* const* d_in, const int* in_sizes, int n_in,
                              void* d_out, int out_size, void* d_ws, size_t ws_size,
                              hipStream_t stream) {
    const float* xq = (const float*)d_in[0];
    const float* xk = (const float*)d_in[1];
    const float* xv = (const float*)d_in[2];
    const float* E  = (const float*)d_in[3];
    const float* Wq = (const float*)d_in[4];
    const float* bq = (const float*)d_in[5];
    const float* Wk = (const float*)d_in[6];
    const float* bk = (const float*)d_in[7];
    const float* Wv = (const float*)d_in[8];
    const float* bv = (const float*)d_in[9];
    const float* Wp = (const float*)d_in[10];
    const float* bp = (const float*)d_in[11];

    float* ws = (float*)d_ws;
    float* qf     = ws;                          // 512*256
    float* kf     = qf + NN * CC;                // 512*256
    float* vf     = kf + NN * CC;                // 512*256
    float* qw     = vf + NN * CC;                // 512*8*256
    float* qbp    = qw + (size_t)NN * HH * CC;   // 512*8
    float* esc    = qbp + NN * HH;               // 512*8*512 (q.k^T scores)
    float* scores = esc + (size_t)NN * HH * NN;  // 512*8*512 (E.qw scores)

    float* out_hidden = (float*)d_out;            // 512*256
    float* out_attn   = out_hidden + NN * CC;     // 8*512*512

    proj_kernel<<<NN, 256, 0, stream>>>(xq, xk, xv, Wq, bq, Wk, bk, Wv, bv, Wp, bp,
                                        qf, kf, vf, qw, qbp);
    fused_score_kernel<<<512 + NN * 8, 256, 0, stream>>>(E, qf, kf, qw, esc, scores);
    softmax_hidden_kernel<<<NN, 512, 0, stream>>>(esc, scores, qbp, vf,
                                                  out_attn, out_hidden);
}